// Round 5
// baseline (271.030 us; speedup 1.0000x reference)
//
#include <hip/hip_runtime.h>

// CTC batch cost, linear-domain, single wave per batch element, PAIRED STEPS.
// ROUND 5: r0-r4 established a ~220cy/step fixed latency term (schedule
// changes r1/r2 neutral, -50% instructions r4 bought only -12%): one exposed
// LDS gather round-trip (~120cy) per time-step, unhoistable past the ring
// ds_write. Fix: process TWO t per iteration (G=2 skew: lane L owns states
// 4L..4L+3 and computes t1=2i-1-2L, t2=2i-2L at iteration i). All 6 gathers
// issue together at iteration top -> latency paid once per 2 t.
//
// Halo mapping (lane L needs A[4L-1](t-1), derived & checked):
//   sub1 (t1): left a3 after t1-1 = left's t2 of iter i-2 -> hB pipe (2-stage,
//     shuffled post-renorm at end of each iteration).
//   sub2 (t2): left a3 after t2-1 = left's t1 of iter i-1 -> hA (shuffled
//     mid-iteration, consumed next iteration).
//   Both values carry epoch e_left(i-2) (hA is pre-renorm of i-1) -> ONE
//   el per iteration (eL pipe, 2-stage) and one shared scale d.
// Renorm every iteration (period 2t, uniform across lanes; pow2-exact ->
// bit-identical true alphas; mantissa >= 2^-47 between renorms, no underflow).
//
// Ring: NSLOT=160 (live span under G=2: newest write 2i+17 minus oldest read
// 2i-127 = 144 <= 160, 8-iteration margin). Rows 0..17 prestaged; row r
// written at iter (r-16)/2, first read at iter (r+1)/2 (8-iter lead). Q: 16
// float2, rows loaded at iter i are written at i+8 (~2800cy >> HBM latency).
// Dormant lanes (t<0) read wrapped slots: pre-zeroed or overwritten with
// finite probs; fully-dormant (a=h=0) -> 0*finite = 0 exact. Live lanes never
// read stale slots (window math above).
//
// Recurrence per sub-step (absmax-0.0 lineage):
//   n0 = (a0 + h) * pb;  n1 = (a1 + a0 + ms1*h) * p0
//   n2 = (a2 + a1) * pb; n3 = (a3 + a2 + ms3*a1) * p1

#define Bc 256
#define Tc 1024
#define Cc 128
#define Uc 100
#define BLANKc 127
#define EPSc 1e-7f
#define LN2f 0.69314718055994530942f
#define RSTRIDE 130            // floats per row slot (float2-aligned)
#define NSLOT 160              // ring depth (span 144 needed)
#define RSB (RSTRIDE*4)        // 520 bytes per row
#define SLOTB (NSLOT*RSB)      // 83200 bytes
#define QD 16                  // staging queue: 16 rows in flight

__global__ __launch_bounds__(64) void ctc_pair_kernel(
    const float* __restrict__ y_pred,     // [B,T,C] post-softmax probs
    const int*   __restrict__ y_true,     // [B,U]
    const int*   __restrict__ label_len,  // [B]
    float*       __restrict__ out)        // [B,1]
{
    __shared__ __align__(16) float rowbuf[NSLOT * RSTRIDE];
    __shared__ float shA[204];
    __shared__ int   shE[64];

    const int b    = blockIdx.x;
    const int lane = threadIdx.x;                  // 0..63
    const float* gp = y_pred + (size_t)b * (Tc * Cc);
    char* rb = (char*)rowbuf;

    // ---- per-lane label classes & skip masks (time-invariant) ----
    const int k0  = 2*lane, k1 = 2*lane+1;
    const int k0c = k0 < Uc ? k0 : Uc-1;
    const int k1c = k1 < Uc ? k1 : Uc-1;
    const int y0  = y_true[b*Uc + k0c];            // class of state 4L+1
    const int y1  = y_true[b*Uc + k1c];            // class of state 4L+3
    int ym1 = y0;
    if (lane > 0) ym1 = y_true[b*Uc + k0 - 1];
    const float ms1 = (lane > 0 && y0 != ym1) ? 1.0f : 0.0f;
    const float ms3 = (y1 != y0) ? 1.0f : 0.0f;
    const float mh  = (lane > 0) ? 1.0f : 0.0f;    // lane 0 has no left halo
    const int y0b = y0 * 4, y1b = y1 * 4;
    const int lane2 = lane * 2, lane8 = lane * 8;

    // ---- t=0 init (only lane 0 holds mass) ----
    float a0=0.f, a1=0.f, a2=0.f, a3=0.f;
    if (lane == 0) { a0 = gp[BLANKc]+EPSc; a1 = gp[y0]+EPSc; }
    int e = 0;

    // ---- pre-zero ring (wrapped/dormant reads = finite/zero, no NaN) ----
    {
        const float4 z = make_float4(0.f,0.f,0.f,0.f);
        float4* rb4 = (float4*)rowbuf;             // 5200 float4
#pragma unroll
        for (int i = 0; i < 81; ++i) rb4[i*64 + lane] = z;
        if (lane < 16) rb4[81*64 + lane] = z;
    }

    // ---- pre-stage rows 0..17 WITH EPS (coalesced float4 reads) ----
#pragma unroll
    for (int i = 0; i < 9; ++i) {
        const int f4  = i*64 + lane;               // 576 float4 = 18 rows
        const int row = f4 >> 5;
        const int c4  = (f4 & 31) * 4;
        float4 v = *(const float4*)(gp + row*Cc + c4);
        float* dst = &rowbuf[row*RSTRIDE + c4];
        dst[0]=v.x+EPSc; dst[1]=v.y+EPSc; dst[2]=v.z+EPSc; dst[3]=v.w+EPSc;
    }
    // single wave: LDS writes/reads are program-ordered; no barrier needed.

    // ---- staging queue: rows 18..33 in flight ----
    float2 Q[QD];
#pragma unroll
    for (int k = 0; k < QD; ++k)
        Q[k] = *(const float2*)(gp + (18+k)*Cc + lane2);

    // ---- incremental ring byte offsets ----
    int r0 = 1 - lane2; r0 %= NSLOT; if (r0 < 0) r0 += NSLOT;
    int sprev = r0*RSB - RSB; if (sprev < 0) sprev += SLOTB;   // pre-decr
    int wprev = 16*RSB;                            // iter1 w1 = row18
    int n2 = 2;                                    // n2 = 2*i

    // ---- halo pipes ----
    float hA1 = 0.f, hB1 = 0.f, hB2 = 0.f;
    int   eL1 = 0,   eL2 = 0;

    auto iter = [&](int j, bool fzp) {
        // -- gather both rows' probs (6 ds_read, issued together) --
        int s1 = sprev + RSB; if (s1 >= SLOTB) s1 -= SLOTB;    // row t1
        int s2 = s1 + RSB;    if (s2 >= SLOTB) s2 -= SLOTB;    // row t2
        sprev = s2;
        const float pb1 = *(const float*)(rb + s1 + BLANKc*4);
        const float p01 = *(const float*)(rb + s1 + y0b);
        const float p11 = *(const float*)(rb + s1 + y1b);
        const float pb2 = *(const float*)(rb + s2 + BLANKc*4);
        const float p02 = *(const float*)(rb + s2 + y0b);
        const float p12 = *(const float*)(rb + s2 + y1b);
        // -- stage rows n2+16, n2+17 (loaded 8 iters ago); reload +32,+33 --
        int w1 = wprev + 2*RSB; if (w1 >= SLOTB) w1 -= SLOTB;
        int w2 = w1 + RSB;      if (w2 >= SLOTB) w2 -= SLOTB;
        wprev = w1;
        float2 qa = Q[2*j], qb = Q[2*j+1];
        qa.x += EPSc; qa.y += EPSc; qb.x += EPSc; qb.y += EPSc;
        *(float2*)(rb + w1 + lane8) = qa;
        *(float2*)(rb + w2 + lane8) = qb;
        int lr1 = n2 + 32; lr1 = lr1 > Tc-1 ? Tc-1 : lr1;
        int lr2 = n2 + 33; lr2 = lr2 > Tc-1 ? Tc-1 : lr2;
        Q[2*j]   = *(const float2*)(gp + lr1*Cc + lane2);
        Q[2*j+1] = *(const float2*)(gp + lr2*Cc + lane2);
        // -- halo scales (both halos carry epoch e_left(i-2) = eL2) --
        const int el = eL2;
        int d = el - e; d = d > 126 ? 126 : d;
        const float h1 = mh * ldexpf(hB2, d);      // for sub1
        const float h2 = mh * ldexpf(hA1, d);      // for sub2
        // -- sub-step 1: t1 = n2-1-lane2 --
        {
            const float n0 = (a0 + h1) * pb1;
            const float n1 = (a1 + a0 + ms1*h1) * p01;
            const float nv = (a2 + a1) * pb1;
            const float n3 = (a3 + a2 + ms3*a1) * p11;
            bool upd = true;
            if (fzp) upd = (lane2 >= n2 - 1024);   // t1 <= 1023
            if (upd) { a0=n0; a1=n1; a2=nv; a3=n3; }
        }
        const float haNew = __shfl_up(a3, 1, 64);  // left's post-sub1 a3
        // -- sub-step 2: t2 = n2-lane2 --
        {
            const float n0 = (a0 + h2) * pb2;
            const float n1 = (a1 + a0 + ms1*h2) * p02;
            const float nv = (a2 + a1) * pb2;
            const float n3 = (a3 + a2 + ms3*a1) * p12;
            bool upd = true;
            if (fzp) upd = (lane2 >= n2 - 1023);   // t2 <= 1023
            if (upd) { a0=n0; a1=n1; a2=nv; a3=n3; }
        }
        // -- renorm (every iteration; pow2-exact; dormant adopts left epoch)
        {
            const float m = fmaxf(fmaxf(a0,a1), fmaxf(a2,a3));
            int ex = (int)((__float_as_uint(m) >> 23) & 0xFF) - 127;
            ex = (m > 0.0f) ? ex : (el - e);
            a0 = ldexpf(a0,-ex); a1 = ldexpf(a1,-ex);
            a2 = ldexpf(a2,-ex); a3 = ldexpf(a3,-ex);
            e += ex;
        }
        // -- pipe shifts: hB/eL post-renorm, hA mid-iteration value --
        hB2 = hB1; hB1 = __shfl_up(a3, 1, 64);
        eL2 = eL1; eL1 = __shfl_up(e , 1, 64);
        hA1 = haNew;
        n2 += 2;
    };

    // ---- iterations i = 1..568 (1136 t; lane 50 ends t=1023 at i=562) ----
    for (int c = 0; c < 63; ++c) {                 // i = 1..504: no freeze
#pragma unroll
        for (int j = 0; j < 8; ++j) iter(j, false);
    }
    for (int c = 0; c < 8; ++c) {                  // i = 505..568 (freeze
#pragma unroll                                     //  predicate inert <512)
        for (int j = 0; j < 8; ++j) iter(j, true);
    }

    // ---- epilogue: loss = -ln( A[2L-1] + A[2L] ), A = a * 2^e ----
    if (lane < 51) {
        shA[4*lane+0] = a0; shA[4*lane+1] = a1;
        shA[4*lane+2] = a2; shA[4*lane+3] = a3;
        shE[lane] = e;
    }
    __syncthreads();                               // one-time, post-loop
    if (lane == 0) {
        const int L  = label_len[b];
        const int s1 = 2*L - 1, s2 = 2*L;
        const float v1 = shA[s1], v2 = shA[s2];
        const int   e1 = shE[s1 >> 2], e2 = shE[s2 >> 2];
        const int   em = e1 > e2 ? e1 : e2;
        const float sum = ldexpf(v1, e1-em) + ldexpf(v2, e2-em);
        const float r   = __log2f(sum) + (float)em;
        out[b] = -LN2f * r;
    }
}

extern "C" void kernel_launch(void* const* d_in, const int* in_sizes, int n_in,
                              void* d_out, int out_size, void* d_ws, size_t ws_size,
                              hipStream_t stream) {
    const float* y_pred    = (const float*)d_in[0];
    const int*   y_true    = (const int*)d_in[1];
    const int*   label_len = (const int*)d_in[2];
    float*       out       = (float*)d_out;
    ctc_pair_kernel<<<Bc, 64, 0, stream>>>(y_pred, y_true, label_len, out);
}